// Round 12
// baseline (136.678 us; speedup 1.0000x reference)
//
#include <hip/hip_runtime.h>
#include <math.h>

#define N_EMBD    4096
#define N_EXPERTS 64
#define N_TOKENS  16384
#define TAU       1e-3f
#define BM        32                  // tokens per block (2 M-tiles per wave)
#define BK        128                 // K per tile
#define NTILES    (N_EMBD / BK)       // 32
#define PLANE     8192                // one bf16 plane: 32 rows x 256 B
#define BUFB      (2 * PLANE)         // hi+lo planes per buffer

typedef __attribute__((ext_vector_type(8))) short bf16x8;
typedef __attribute__((ext_vector_type(4))) float f32x4;

#define MFMA16 __builtin_amdgcn_mfma_f32_16x16x32_bf16

struct hl_pair { unsigned h, l; };

// ---------------------------------------------------------------------------
// f32 -> (bf16 hi, bf16 lo) RNE split, pair-packed into one u32 each.
// ---------------------------------------------------------------------------
__device__ __forceinline__ hl_pair split_pair(float f0, float f1) {
    unsigned u0 = __builtin_bit_cast(unsigned, f0);
    unsigned u1 = __builtin_bit_cast(unsigned, f1);
    unsigned r0 = u0 + 0x7FFFu + ((u0 >> 16) & 1u);
    unsigned r1 = u1 + 0x7FFFu + ((u1 >> 16) & 1u);
    hl_pair p;
    p.h = (r0 >> 16) | (r1 & 0xFFFF0000u);
    float h0 = __builtin_bit_cast(float, r0 & 0xFFFF0000u);
    float h1 = __builtin_bit_cast(float, r1 & 0xFFFF0000u);
    float l0 = f0 - h0;
    float l1 = f1 - h1;
    unsigned v0 = __builtin_bit_cast(unsigned, l0);
    unsigned v1 = __builtin_bit_cast(unsigned, l1);
    unsigned s0 = v0 + 0x7FFFu + ((v0 >> 16) & 1u);
    unsigned s1 = v1 + 0x7FFFu + ((v1 >> 16) & 1u);
    p.l = (s0 >> 16) | (s1 & 0xFFFF0000u);
    return p;
}

// ---------------------------------------------------------------------------
// Kernel 0: pack W into bf16 hi/lo MFMA B-fragments; zero the flag counter.
// Frag F = ks*8 + nt*2 + term. Lane l elem j = W[nt*16+(l&15)][ks*32+(l>>4)*8+j]
// ---------------------------------------------------------------------------
__global__ void w_pack_bf16(const float* __restrict__ W,
                            uint4* __restrict__ Bpack,
                            int* __restrict__ flags) {
    int tid = blockIdx.x * blockDim.x + threadIdx.x;   // 32768
    if (tid == 0) flags[0] = 0;
    int lane = tid & 63;
    int nt   = (tid >> 6) & 3;
    int ks   = tid >> 8;                               // 0..127
    int e = nt * 16 + (lane & 15);
    int k = ks * 32 + ((lane >> 4) << 3);
    const float* src = W + (size_t)e * N_EMBD + k;
    uint4 hp, lp;
    hl_pair p0 = split_pair(src[0], src[1]);
    hl_pair p1 = split_pair(src[2], src[3]);
    hl_pair p2 = split_pair(src[4], src[5]);
    hl_pair p3 = split_pair(src[6], src[7]);
    hp.x = p0.h; lp.x = p0.l;
    hp.y = p1.h; lp.y = p1.l;
    hp.z = p2.h; lp.z = p2.l;
    hp.w = p3.h; lp.w = p3.l;
    size_t F = (size_t)ks * 8 + nt * 2;
    Bpack[F * 64 + lane]       = hp;
    Bpack[(F + 1) * 64 + lane] = lp;
}

// ---------------------------------------------------------------------------
// Split one float4 of x into bf16 hi/lo and store to swizzled LDS planes.
// hi plane at buf+[0,PLANE), lo plane at buf+[PLANE,2*PLANE).
// ---------------------------------------------------------------------------
__device__ __forceinline__ void store_split(char* buf, int off, f32x4 v) {
    hl_pair p01 = split_pair(v.x, v.y);
    hl_pair p23 = split_pair(v.z, v.w);
    uint2 hw, lw;
    hw.x = p01.h; hw.y = p23.h;
    lw.x = p01.l; lw.y = p23.l;
    *(uint2*)(buf + off)         = hw;
    *(uint2*)(buf + off + PLANE) = lw;
}

// ---------------------------------------------------------------------------
// Kernel 1: fused router. Block = 32 tokens x 4 waves; wave w owns experts
// [w*16, w*16+16) over BOTH 16-token M-tiles (2 accs) -> per-block B bytes
// amortized over 2x tokens vs r10 (B total 1GB -> 512MB).
// Reg-staged A (global->VGPR->split->swizzled LDS planes), double-buffered,
// raw s_barrier + lgkmcnt(0) only (no vmcnt drain at barriers).
// Load-order discipline: vmem ops retire IN ORDER, so A-prefetch loads are
// issued at the END of each iteration (after all B loads) -- waiting on B
// then never force-drains the young A loads.
// Swizzle: physical = logical ^ ((row&7)<<4), both sides (rule #21).
// ---------------------------------------------------------------------------
__global__ __launch_bounds__(256, 2) void router_fused(
        const float* __restrict__ x,
        const uint4* __restrict__ Bpack,
        float* __restrict__ out,
        int* __restrict__ flags) {
    __shared__ __align__(16) char ldsA[2 * BUFB];   // 2 bufs x {hi,lo} planes
    __shared__ float red[BM][64];

    const int tid  = threadIdx.x;
    const int lane = tid & 63;
    const int w    = tid >> 6;                  // wave = expert quarter
    const int tok0 = blockIdx.x * BM;
    const int l15 = lane & 15, l16 = lane >> 4;

    // staging geometry: thread covers rows {row0+8j, j=0..3}, float4 col k4
    const int k4   = tid & 31;
    const int row0 = tid >> 5;                  // 0..7
    const f32x4* g0 = (const f32x4*)x + (size_t)(tok0 + row0     ) * (N_EMBD / 4) + k4;
    const f32x4* g1 = (const f32x4*)x + (size_t)(tok0 + row0 +  8) * (N_EMBD / 4) + k4;
    const f32x4* g2 = (const f32x4*)x + (size_t)(tok0 + row0 + 16) * (N_EMBD / 4) + k4;
    const f32x4* g3 = (const f32x4*)x + (size_t)(tok0 + row0 + 24) * (N_EMBD / 4) + k4;
    const int swz = (row0 & 7) << 4;            // row&7 identical for all 4 rows
    const int wo0 = (((row0     ) * 256) + k4 * 8) ^ swz;
    const int wo1 = (((row0 +  8) * 256) + k4 * 8) ^ swz;
    const int wo2 = (((row0 + 16) * 256) + k4 * 8) ^ swz;
    const int wo3 = (((row0 + 24) * 256) + k4 * 8) ^ swz;

    // fragment read offsets (M-tile 0; M-tile 1 = +4096), full-logical XOR
    const int swz_r = (l15 & 7) << 4;
    int ro[4];
#pragma unroll
    for (int ksl = 0; ksl < 4; ++ksl)
        ro[ksl] = (l15 * 256 + l16 * 16 + ksl * 64) ^ swz_r;

    f32x4 acc0 = {0.f, 0.f, 0.f, 0.f};
    f32x4 acc1 = {0.f, 0.f, 0.f, 0.f};

    f32x4 ra0, ra1, ra2, ra3, rb0, rb1, rb2, rb3;
    char* buf0 = ldsA;
    char* buf1 = ldsA + BUFB;

#define LOADA(P, t) { P##0 = g0[(t) * 32]; P##1 = g1[(t) * 32];               \
                      P##2 = g2[(t) * 32]; P##3 = g3[(t) * 32]; }
#define STOREA(buf, P) { store_split(buf, wo0, P##0); store_split(buf, wo1, P##1); \
                         store_split(buf, wo2, P##2); store_split(buf, wo3, P##3); }
#define COMPUTE(bufR, tt) {                                                   \
    const uint4* bq = Bpack + ((size_t)((tt) * 32 + w * 2)) * 64 + lane;      \
    _Pragma("unroll")                                                         \
    for (int ksl = 0; ksl < 4; ++ksl) {                                       \
        uint4 bhq = bq[ksl * 512];                                            \
        uint4 blq = bq[ksl * 512 + 64];                                       \
        bf16x8 bh = __builtin_bit_cast(bf16x8, bhq);                          \
        bf16x8 bl = __builtin_bit_cast(bf16x8, blq);                          \
        bf16x8 ah0 = *(const bf16x8*)((bufR) + ro[ksl]);                      \
        bf16x8 al0 = *(const bf16x8*)((bufR) + ro[ksl] + PLANE);              \
        acc0 = MFMA16(ah0, bh, acc0, 0, 0, 0);                                \
        acc0 = MFMA16(ah0, bl, acc0, 0, 0, 0);                                \
        acc0 = MFMA16(al0, bh, acc0, 0, 0, 0);                                \
        bf16x8 ah1 = *(const bf16x8*)((bufR) + ro[ksl] + 4096);               \
        bf16x8 al1 = *(const bf16x8*)((bufR) + ro[ksl] + 4096 + PLANE);       \
        acc1 = MFMA16(ah1, bh, acc1, 0, 0, 0);                                \
        acc1 = MFMA16(ah1, bl, acc1, 0, 0, 0);                                \
        acc1 = MFMA16(al1, bh, acc1, 0, 0, 0);                                \
    } }

    // prologue: stage tile 0; prefetch tiles 1 (rb) and 2 (ra)
    LOADA(rb, 0);
    STOREA(buf0, rb);                      // one-time vmcnt stall
    LOADA(rb, 1);
    LOADA(ra, 2);
    asm volatile("s_waitcnt lgkmcnt(0)" ::: "memory");
    __builtin_amdgcn_s_barrier();
    __builtin_amdgcn_sched_barrier(0);

    for (int t = 0; t < NTILES; t += 2) {
        // ---- tile t (buf0) ----
        COMPUTE(buf0, t);
        STOREA(buf1, rb);                  // tile t+1 -> buf1 (rb arrived long ago)
        asm volatile("s_waitcnt lgkmcnt(0)" ::: "memory");
        __builtin_amdgcn_s_barrier();
        __builtin_amdgcn_sched_barrier(0);

        // ---- tile t+1 (buf1) ----
        COMPUTE(buf1, t + 1);
        if (t + 2 < NTILES) {
            STOREA(buf0, ra);              // tile t+2 -> buf0
            // A-prefetch LAST (after all B loads of this iteration):
            if (t + 3 < NTILES) LOADA(rb, t + 3);
            if (t + 4 < NTILES) LOADA(ra, t + 4);
            asm volatile("s_waitcnt lgkmcnt(0)" ::: "memory");
            __builtin_amdgcn_s_barrier();
            __builtin_amdgcn_sched_barrier(0);
        }
    }
#undef LOADA
#undef STOREA
#undef COMPUTE

    // C layout: row(token in M-tile) = (lane>>4)*4 + reg, col = lane&15
    const int rb_ = l16 << 2;
#pragma unroll
    for (int j = 0; j < 4; ++j) {
        red[rb_ + j][w * 16 + l15]      = acc0[j];
        red[16 + rb_ + j][w * 16 + l15] = acc1[j];
    }
    __syncthreads();

    // wave w finalizes tokens w*8 .. w*8+7; lane = expert
    for (int tt = 0; tt < 8; ++tt) {
        const int t = w * 8 + tt;
        float v = red[t][lane];

        float m1 = v; int i1 = lane;
#pragma unroll
        for (int off = 32; off; off >>= 1) {
            float ov = __shfl_xor(m1, off); int oi = __shfl_xor(i1, off);
            if (ov > m1 || (ov == m1 && oi < i1)) { m1 = ov; i1 = oi; }
        }
        float m2 = (lane == i1) ? -INFINITY : v; int i2 = lane;
#pragma unroll
        for (int off = 32; off; off >>= 1) {
            float ov = __shfl_xor(m2, off); int oi = __shfl_xor(i2, off);
            if (ov > m2 || (ov == m2 && oi < i2)) { m2 = ov; i2 = oi; }
        }
        float m3 = (lane == i1 || lane == i2) ? -INFINITY : v;
#pragma unroll
        for (int off = 32; off; off >>= 1)
            m3 = fmaxf(m3, __shfl_xor(m3, off));

        if (lane == 0) {
            const int tok = tok0 + t;
            float e2  = __expf(m2 - m1);
            float inv = 1.0f / (1.0f + e2);
            float2 idx = make_float2((float)i1, (float)i2);
            float2 gts = make_float2(inv, e2 * inv);
            *(float2*)(out + 2 * tok) = idx;
            *(float2*)(out + 2 * N_TOKENS + 2 * tok) = gts;
            if ((m1 - m2 < TAU) || (m2 - m3 < TAU)) {
                int p = atomicAdd(flags, 1);
                if (p < N_TOKENS) flags[1 + p] = tok;
            }
        }
    }
}

// ---------------------------------------------------------------------------
// Kernel 2: exact f64 refinement of flagged near-tie tokens. Block per token
// (grid-strided). Wave wv handles experts wv*16..+16, lanes split K.
// ---------------------------------------------------------------------------
__global__ __launch_bounds__(256) void refine(const float* __restrict__ x,
                                              const float* __restrict__ W,
                                              const int* __restrict__ flags,
                                              float* __restrict__ out) {
    __shared__ double redd[64];
    const int lane = threadIdx.x & 63;
    const int wv   = threadIdx.x >> 6;
    int cnt = flags[0];
    if (cnt > N_TOKENS) cnt = N_TOKENS;

    for (int i = blockIdx.x; i < cnt; i += gridDim.x) {
        const int tok = flags[1 + i];
        const float4* xr4 = (const float4*)(x + (size_t)tok * N_EMBD);
#pragma unroll
        for (int ee = 0; ee < 16; ++ee) {
            const int e = wv * 16 + ee;
            const float4* wr = (const float4*)(W + (size_t)e * N_EMBD);
            double acc = 0.0;
#pragma unroll 4
            for (int c = 0; c < 16; ++c) {
                float4 xv = xr4[c * 64 + lane];
                float4 wq = wr[c * 64 + lane];
                acc += (double)xv.x * wq.x + (double)xv.y * wq.y
                     + (double)xv.z * wq.z + (double)xv.w * wq.w;
            }
#pragma unroll
            for (int off = 32; off; off >>= 1)
                acc += __shfl_xor(acc, off);
            if (lane == 0) redd[e] = acc;
        }
        __syncthreads();
        if (wv == 0) {
            double v = redd[lane];
            double m1 = v; int i1 = lane;
#pragma unroll
            for (int off = 32; off; off >>= 1) {
                double ov = __shfl_xor(m1, off); int oi = __shfl_xor(i1, off);
                if (ov > m1 || (ov == m1 && oi < i1)) { m1 = ov; i1 = oi; }
            }
            double m2 = (lane == i1) ? -INFINITY : v; int i2 = lane;
#pragma unroll
            for (int off = 32; off; off >>= 1) {
                double ov = __shfl_xor(m2, off); int oi = __shfl_xor(i2, off);
                if (ov > m2 || (ov == m2 && oi < i2)) { m2 = ov; i2 = oi; }
            }
            if (lane == 0) {
                double e2  = exp(m2 - m1);
                double inv = 1.0 / (1.0 + e2);
                out[2 * tok + 0] = (float)i1;
                out[2 * tok + 1] = (float)i2;
                out[2 * N_TOKENS + 2 * tok + 0] = (float)inv;
                out[2 * N_TOKENS + 2 * tok + 1] = (float)(e2 * inv);
            }
        }
        __syncthreads();
    }
}

// ---------------------------------------------------------------------------
extern "C" void kernel_launch(void* const* d_in, const int* in_sizes, int n_in,
                              void* d_out, int out_size, void* d_ws, size_t ws_size,
                              hipStream_t stream) {
    const float* x = (const float*)d_in[0];
    const float* W = (const float*)d_in[1];
    float* out = (float*)d_out;

    uint4* Bpack = (uint4*)d_ws;                          // [0, 1MB)
    int*   flags = (int*)((char*)d_ws + (2u << 20));      // [2MB, ...)

    w_pack_bf16 <<<128, 256, 0, stream>>>(W, Bpack, flags);
    router_fused<<<N_TOKENS / BM, 256, 0, stream>>>(x, Bpack, out, flags);
    refine      <<<128, 256, 0, stream>>>(x, W, flags, out);
}

// Round 13
// 109.667 us; speedup vs baseline: 1.2463x; 1.2463x over previous
//
#include <hip/hip_runtime.h>
#include <math.h>

#define N_EMBD    4096
#define N_EXPERTS 64
#define N_TOKENS  16384
#define TAU       1e-3f
#define NT_BLK    32                  // tokens per block
#define KS        4                   // K-split across blocks
#define K_BLK     (N_EMBD / KS)       // 1024 f32 per block
#define BK2       64                  // K per LDS tile
#define NT2       (K_BLK / BK2)       // 16 tiles per block

typedef __attribute__((ext_vector_type(8))) short bf16x8;
typedef __attribute__((ext_vector_type(4))) float f32x4;

#define MFMA16 __builtin_amdgcn_mfma_f32_16x16x32_bf16

struct hl_pair { unsigned h, l; };

// ---------------------------------------------------------------------------
// f32 -> (bf16 hi, bf16 lo) RNE split, pair-packed into one u32 each.
// ---------------------------------------------------------------------------
__device__ __forceinline__ hl_pair split_pair(float f0, float f1) {
    unsigned u0 = __builtin_bit_cast(unsigned, f0);
    unsigned u1 = __builtin_bit_cast(unsigned, f1);
    unsigned r0 = u0 + 0x7FFFu + ((u0 >> 16) & 1u);
    unsigned r1 = u1 + 0x7FFFu + ((u1 >> 16) & 1u);
    hl_pair p;
    p.h = (r0 >> 16) | (r1 & 0xFFFF0000u);
    float h0 = __builtin_bit_cast(float, r0 & 0xFFFF0000u);
    float h1 = __builtin_bit_cast(float, r1 & 0xFFFF0000u);
    float l0 = f0 - h0;
    float l1 = f1 - h1;
    unsigned v0 = __builtin_bit_cast(unsigned, l0);
    unsigned v1 = __builtin_bit_cast(unsigned, l1);
    unsigned s0 = v0 + 0x7FFFu + ((v0 >> 16) & 1u);
    unsigned s1 = v1 + 0x7FFFu + ((v1 >> 16) & 1u);
    p.l = (s0 >> 16) | (s1 & 0xFFFF0000u);
    return p;
}

// ---------------------------------------------------------------------------
// Kernel 0: pack W into bf16 hi/lo MFMA B-fragments; zero the flag counter.
// Frag F = ks*8 + nt*2 + term. Lane l elem j = W[nt*16+(l&15)][ks*32+(l>>4)*8+j]
// ---------------------------------------------------------------------------
__global__ void w_pack_bf16(const float* __restrict__ W,
                            uint4* __restrict__ Bpack,
                            int* __restrict__ flags) {
    int tid = blockIdx.x * blockDim.x + threadIdx.x;   // 32768
    if (tid == 0) flags[0] = 0;
    int lane = tid & 63;
    int nt   = (tid >> 6) & 3;
    int ks   = tid >> 8;                               // 0..127
    int e = nt * 16 + (lane & 15);
    int k = ks * 32 + ((lane >> 4) << 3);
    const float* src = W + (size_t)e * N_EMBD + k;
    uint4 hp, lp;
    hl_pair p0 = split_pair(src[0], src[1]);
    hl_pair p1 = split_pair(src[2], src[3]);
    hl_pair p2 = split_pair(src[4], src[5]);
    hl_pair p3 = split_pair(src[6], src[7]);
    hp.x = p0.h; lp.x = p0.l;
    hp.y = p1.h; lp.y = p1.l;
    hp.z = p2.h; lp.z = p2.l;
    hp.w = p3.h; lp.w = p3.l;
    size_t F = (size_t)ks * 8 + nt * 2;
    Bpack[F * 64 + lane]       = hp;
    Bpack[(F + 1) * 64 + lane] = lp;
}

// ---------------------------------------------------------------------------
// Split 8 f32 into bf16 hi/lo uint4s and ds_write_b128 to the two planes.
// ---------------------------------------------------------------------------
__device__ __forceinline__ void store_split8(char* buf, int off, f32x4 a, f32x4 b) {
    hl_pair p0 = split_pair(a.x, a.y);
    hl_pair p1 = split_pair(a.z, a.w);
    hl_pair p2 = split_pair(b.x, b.y);
    hl_pair p3 = split_pair(b.z, b.w);
    uint4 h, l;
    h.x = p0.h; h.y = p1.h; h.z = p2.h; h.w = p3.h;
    l.x = p0.l; l.y = p1.l; l.z = p2.l; l.w = p3.l;
    *(uint4*)(buf + off)        = h;
    *(uint4*)(buf + off + 4096) = l;
}

// ---------------------------------------------------------------------------
// Kernel 1: router GEMM, K-split x4 for occupancy (r12 counters: 23% occ was
// the binding constraint -- grid 512 = 2 blocks/CU; this kernel: grid 2048 =
// 8 blocks/CU = HW max 32 waves/CU, VGPR capped at 64 via launch_bounds).
// Block = 32 tokens x 1 K-quarter; wave w = experts [16w,16w+16), 2 M-tiles.
// Tile BK=64: reg-stage A (1-deep prefetch -- TLP now hides latency),
// split->swizzled LDS planes (conflict-free: 8 lanes/bank-quad = minimum),
// dbuf + raw barrier with lgkmcnt(0) only.
// partial layout: [KS][N_TOKENS][64] f32.
// ---------------------------------------------------------------------------
__global__ __launch_bounds__(256, 8) void router_gemm(
        const float* __restrict__ x,
        const uint4* __restrict__ Bpack,
        float* __restrict__ partial) {
    __shared__ __align__(16) char ldsA[2 * 8192];   // dbuf x {hi 4KB, lo 4KB}

    const int tid  = threadIdx.x;
    const int lane = tid & 63;
    const int w    = tid >> 6;                  // wave = expert quarter
    const int kq   = blockIdx.x & 3;            // K quarter
    const int tok0 = (blockIdx.x >> 2) * NT_BLK;
    const int l15 = lane & 15, l16 = lane >> 4;

    // staging: thread -> row tid>>3 (0..31), 8-f32 chunk c8 = tid&7
    const int row_w = tid >> 3;
    const int c8    = tid & 7;
    const f32x4* g = (const f32x4*)(x + (size_t)(tok0 + row_w) * N_EMBD
                                      + kq * K_BLK + c8 * 8);
    const int wo = row_w * 128 + ((c8 * 16) ^ ((row_w & 7) << 4));

    // fragment read offsets: K-step s in {0,1}, M-tile m in {0,1} (+2048)
    const int swz_r = (l15 & 7) << 4;
    const int ro0 = l15 * 128 + ((l16 * 16)      ^ swz_r);
    const int ro1 = l15 * 128 + ((64 + l16 * 16) ^ swz_r);

    f32x4 acc0 = {0.f, 0.f, 0.f, 0.f};
    f32x4 acc1 = {0.f, 0.f, 0.f, 0.f};
    f32x4 ra0, ra1;

    char* buf0 = ldsA;
    char* buf1 = ldsA + 8192;

    // B frag base: F = (kq*32 + t*2 + s)*8 + w*2 (+1 for lo term)
    const uint4* bbase = Bpack + ((size_t)(kq * 32) * 8 + w * 2) * 64 + lane;

#define LOADA(t) { ra0 = g[(t) * 16]; ra1 = g[(t) * 16 + 1]; }
#define STOREA(buf) store_split8(buf, wo, ra0, ra1)
#define COMPUTE(bufR, tt) {                                                   \
    const uint4* bq = bbase + (size_t)(tt) * 1024;                            \
    uint4 bh0q = bq[0];   uint4 bl0q = bq[64];                                \
    uint4 bh1q = bq[512]; uint4 bl1q = bq[576];                               \
    bf16x8 bh0 = __builtin_bit_cast(bf16x8, bh0q);                            \
    bf16x8 bl0 = __builtin_bit_cast(bf16x8, bl0q);                            \
    bf16x8 bh1 = __builtin_bit_cast(bf16x8, bh1q);                            \
    bf16x8 bl1 = __builtin_bit_cast(bf16x8, bl1q);                            \
    bf16x8 a;                                                                 \
    a = *(const bf16x8*)((bufR) + ro0);                                       \
    acc0 = MFMA16(a, bh0, acc0, 0, 0, 0);                                     \
    acc0 = MFMA16(a, bl0, acc0, 0, 0, 0);                                     \
    a = *(const bf16x8*)((bufR) + ro0 + 4096);                                \
    acc0 = MFMA16(a, bh0, acc0, 0, 0, 0);                                     \
    a = *(const bf16x8*)((bufR) + ro0 + 2048);                                \
    acc1 = MFMA16(a, bh0, acc1, 0, 0, 0);                                     \
    acc1 = MFMA16(a, bl0, acc1, 0, 0, 0);                                     \
    a = *(const bf16x8*)((bufR) + ro0 + 2048 + 4096);                         \
    acc1 = MFMA16(a, bh0, acc1, 0, 0, 0);                                     \
    a = *(const bf16x8*)((bufR) + ro1);                                       \
    acc0 = MFMA16(a, bh1, acc0, 0, 0, 0);                                     \
    acc0 = MFMA16(a, bl1, acc0, 0, 0, 0);                                     \
    a = *(const bf16x8*)((bufR) + ro1 + 4096);                                \
    acc0 = MFMA16(a, bh1, acc0, 0, 0, 0);                                     \
    a = *(const bf16x8*)((bufR) + ro1 + 2048);                                \
    acc1 = MFMA16(a, bh1, acc1, 0, 0, 0);                                     \
    acc1 = MFMA16(a, bl1, acc1, 0, 0, 0);                                     \
    a = *(const bf16x8*)((bufR) + ro1 + 2048 + 4096);                         \
    acc1 = MFMA16(a, bh1, acc1, 0, 0, 0);                                     \
}

    // prologue: stage tile 0; prefetch tile 1
    LOADA(0);
    STOREA(buf0);
    LOADA(1);
    asm volatile("s_waitcnt lgkmcnt(0)" ::: "memory");
    __builtin_amdgcn_s_barrier();
    __builtin_amdgcn_sched_barrier(0);

    for (int t = 0; t < NT2; t += 2) {
        COMPUTE(buf0, t);
        STOREA(buf1);                          // tile t+1
        if (t + 2 < NT2) LOADA(t + 2);
        asm volatile("s_waitcnt lgkmcnt(0)" ::: "memory");
        __builtin_amdgcn_s_barrier();
        __builtin_amdgcn_sched_barrier(0);

        COMPUTE(buf1, t + 1);
        if (t + 2 < NT2) {
            STOREA(buf0);                      // tile t+2
            if (t + 3 < NT2) LOADA(t + 3);
            asm volatile("s_waitcnt lgkmcnt(0)" ::: "memory");
            __builtin_amdgcn_s_barrier();
            __builtin_amdgcn_sched_barrier(0);
        }
    }
#undef LOADA
#undef STOREA
#undef COMPUTE

    // C layout: row(token in M-tile) = l16*4 + j, col(expert in quarter) = l15
    float* po = partial + ((size_t)kq * N_TOKENS + tok0) * 64 + w * 16 + l15;
#pragma unroll
    for (int j = 0; j < 4; ++j) {
        po[(size_t)(l16 * 4 + j) * 64]        = acc0[j];
        po[(size_t)(16 + l16 * 4 + j) * 64]   = acc1[j];
    }
}

// ---------------------------------------------------------------------------
// Kernel 2: finalize. Wave per token; sum 4 K-quarter partials; top-3
// butterflies; softmax of top-2; near-tie flagging for refine.
// ---------------------------------------------------------------------------
__global__ void finalize(const float* __restrict__ partial,
                         float* __restrict__ out,
                         int* __restrict__ flags) {
    const int lane = threadIdx.x & 63;
    const int tok  = blockIdx.x * 4 + (threadIdx.x >> 6);

    float v = partial[(size_t)tok * 64 + lane]
            + partial[((size_t)N_TOKENS + tok) * 64 + lane]
            + partial[((size_t)2 * N_TOKENS + tok) * 64 + lane]
            + partial[((size_t)3 * N_TOKENS + tok) * 64 + lane];

    float m1 = v; int i1 = lane;
#pragma unroll
    for (int off = 32; off; off >>= 1) {
        float ov = __shfl_xor(m1, off); int oi = __shfl_xor(i1, off);
        if (ov > m1 || (ov == m1 && oi < i1)) { m1 = ov; i1 = oi; }
    }
    float m2 = (lane == i1) ? -INFINITY : v; int i2 = lane;
#pragma unroll
    for (int off = 32; off; off >>= 1) {
        float ov = __shfl_xor(m2, off); int oi = __shfl_xor(i2, off);
        if (ov > m2 || (ov == m2 && oi < i2)) { m2 = ov; i2 = oi; }
    }
    float m3 = (lane == i1 || lane == i2) ? -INFINITY : v;
#pragma unroll
    for (int off = 32; off; off >>= 1)
        m3 = fmaxf(m3, __shfl_xor(m3, off));

    if (lane == 0) {
        float e2  = __expf(m2 - m1);
        float inv = 1.0f / (1.0f + e2);
        float2 idx = make_float2((float)i1, (float)i2);
        float2 gts = make_float2(inv, e2 * inv);
        *(float2*)(out + 2 * tok) = idx;
        *(float2*)(out + 2 * N_TOKENS + 2 * tok) = gts;
        if ((m1 - m2 < TAU) || (m2 - m3 < TAU)) {
            int p = atomicAdd(flags, 1);
            if (p < N_TOKENS) flags[1 + p] = tok;
        }
    }
}

// ---------------------------------------------------------------------------
// Kernel 3: exact f64 refinement of flagged near-tie tokens. Block per token
// (grid-strided). Wave wv handles experts wv*16..+16, lanes split K.
// ---------------------------------------------------------------------------
__global__ __launch_bounds__(256) void refine(const float* __restrict__ x,
                                              const float* __restrict__ W,
                                              const int* __restrict__ flags,
                                              float* __restrict__ out) {
    __shared__ double redd[64];
    const int lane = threadIdx.x & 63;
    const int wv   = threadIdx.x >> 6;
    int cnt = flags[0];
    if (cnt > N_TOKENS) cnt = N_TOKENS;

    for (int i = blockIdx.x; i < cnt; i += gridDim.x) {
        const int tok = flags[1 + i];
        const float4* xr4 = (const float4*)(x + (size_t)tok * N_EMBD);
#pragma unroll
        for (int ee = 0; ee < 16; ++ee) {
            const int e = wv * 16 + ee;
            const float4* wr = (const float4*)(W + (size_t)e * N_EMBD);
            double acc = 0.0;
#pragma unroll 4
            for (int c = 0; c < 16; ++c) {
                float4 xv = xr4[c * 64 + lane];
                float4 wq = wr[c * 64 + lane];
                acc += (double)xv.x * wq.x + (double)xv.y * wq.y
                     + (double)xv.z * wq.z + (double)xv.w * wq.w;
            }
#pragma unroll
            for (int off = 32; off; off >>= 1)
                acc += __shfl_xor(acc, off);
            if (lane == 0) redd[e] = acc;
        }
        __syncthreads();
        if (wv == 0) {
            double v = redd[lane];
            double m1 = v; int i1 = lane;
#pragma unroll
            for (int off = 32; off; off >>= 1) {
                double ov = __shfl_xor(m1, off); int oi = __shfl_xor(i1, off);
                if (ov > m1 || (ov == m1 && oi < i1)) { m1 = ov; i1 = oi; }
            }
            double m2 = (lane == i1) ? -INFINITY : v; int i2 = lane;
#pragma unroll
            for (int off = 32; off; off >>= 1) {
                double ov = __shfl_xor(m2, off); int oi = __shfl_xor(i2, off);
                if (ov > m2 || (ov == m2 && oi < i2)) { m2 = ov; i2 = oi; }
            }
            if (lane == 0) {
                double e2  = exp(m2 - m1);
                double inv = 1.0 / (1.0 + e2);
                out[2 * tok + 0] = (float)i1;
                out[2 * tok + 1] = (float)i2;
                out[2 * N_TOKENS + 2 * tok + 0] = (float)inv;
                out[2 * N_TOKENS + 2 * tok + 1] = (float)(e2 * inv);
            }
        }
        __syncthreads();
    }
}

// ---------------------------------------------------------------------------
extern "C" void kernel_launch(void* const* d_in, const int* in_sizes, int n_in,
                              void* d_out, int out_size, void* d_ws, size_t ws_size,
                              hipStream_t stream) {
    const float* x = (const float*)d_in[0];
    const float* W = (const float*)d_in[1];
    float* out = (float*)d_out;

    uint4* Bpack   = (uint4*)d_ws;                           // [0, 1MB)
    int*   flags   = (int*)((char*)d_ws + (1u << 20));       // [1MB, 1MB+64KB)
    float* partial = (float*)((char*)d_ws + (2u << 20));     // [2MB, 18MB)

    w_pack_bf16<<<128, 256, 0, stream>>>(W, Bpack, flags);
    router_gemm<<<(N_TOKENS / NT_BLK) * KS, 256, 0, stream>>>(x, Bpack, partial);
    finalize   <<<N_TOKENS / 4, 256, 0, stream>>>(partial, out, flags);
    refine     <<<128, 256, 0, stream>>>(x, W, flags, out);
}